// Round 13
// baseline (183.314 us; speedup 1.0000x reference)
//
#include <hip/hip_runtime.h>
#include <hip/hip_bf16.h>
#include <stdint.h>

#define D_MODEL 1024
#define HEAD_DIM 128
#define NUM_HEADS 8
#define SEQ 4096

using bf16x8 = __attribute__((ext_vector_type(8))) short;
using f32x4  = __attribute__((ext_vector_type(4))) float;

__device__ __forceinline__ unsigned short f32_to_bf16(float f) {
    union { float f; uint32_t u; } c{f};
    uint32_t u = c.u;
    return (unsigned short)((u + 0x7fffu + ((u >> 16) & 1u)) >> 16);
}
__device__ __forceinline__ uint32_t pack_bf16x2(float lo, float hi) {
    return (uint32_t)f32_to_bf16(lo) | ((uint32_t)f32_to_bf16(hi) << 16);
}
// packed f32x2 -> bf16x2 (low = first arg); HW instr on gfx950
__device__ __forceinline__ uint32_t cvt2_bf16(float a, float b) {
#if __has_builtin(__builtin_amdgcn_cvt_pk_bf16_f32)
    auto r = __builtin_amdgcn_cvt_pk_bf16_f32(a, b);
    union { decltype(r) v; uint32_t u; } c; c.v = r;
    return c.u;
#else
    return pack_bf16x2(a, b);
#endif
}

// async global->LDS, 16B per lane; LDS dest = uniform base + lane*16
__device__ __forceinline__ void dma16(const void* g, void* l) {
    __builtin_amdgcn_global_load_lds(
        (const __attribute__((address_space(1))) unsigned int*)g,
        (__attribute__((address_space(3))) unsigned int*)l, 16, 0, 0);
}

// ---------------- kernel 0: prep (cvt_x + pack Wt) ----------
// blocks [0,2048): x fp32->bf16 ; blocks [2048,2368): Wt[n][k]=W[k][n] bf16
__global__ __launch_bounds__(256) void prep(
    const float4* __restrict__ x, int4* __restrict__ xb,
    const float* __restrict__ Wq, const float* __restrict__ Wk,
    const float* __restrict__ Wv, unsigned short* __restrict__ Wt)
{
    __shared__ unsigned short tile[64][72];
    const int t = threadIdx.x;
    if (blockIdx.x < 2048) {
        int i = blockIdx.x * 256 + t;
        float4 a = x[2 * i], b = x[2 * i + 1];
        int4 o;
        o.x = (int)cvt2_bf16(a.x, a.y);
        o.y = (int)cvt2_bf16(a.z, a.w);
        o.z = (int)cvt2_bf16(b.x, b.y);
        o.w = (int)cvt2_bf16(b.z, b.w);
        xb[i] = o;
        return;
    }
    int bt = blockIdx.x - 2048;      // 0..319
    int ktile = bt & 15, ntile = bt >> 4;
    int k0 = ktile * 64, n0 = ntile * 64;
    const float* W; int ldw, nc0;
    if (n0 < 1024)      { W = Wq; ldw = 1024; nc0 = n0; }
    else if (n0 < 1152) { W = Wk; ldw = 128;  nc0 = n0 - 1024; }
    else                { W = Wv; ldw = 128;  nc0 = n0 - 1152; }
    int c = t & 63, r0 = t >> 6;
#pragma unroll
    for (int p = 0; p < 16; ++p) {
        int r = r0 + p * 4;
        tile[c][r] = f32_to_bf16(W[(k0 + r) * ldw + nc0 + c]);
    }
    __syncthreads();
#pragma unroll
    for (int p = 0; p < 16; ++p) {
        int rn = r0 + p * 4;
        Wt[(n0 + rn) * 1024 + k0 + c] = tile[rn][c];
    }
}

// ---------------- kernel 1: QKV projection GEMM -------------
// m97-style 128x128 tiles (grid x=m 32, y=n 10 -> 320 blocks, 64KB LDS,
// 2 blocks/CU, 32 MFMA per wave-iter). DMA-staged, XOR-swizzled, dbuf.
// y<8: pure q (scaled). y=8: pure k. y=9: pure v -> in-LDS transpose -> vt.
__global__ __launch_bounds__(256, 2) void qkv_gemm(
    const unsigned short* __restrict__ xb,   // [4096][1024]
    const unsigned short* __restrict__ Wt,   // [1280][1024]
    const float* __restrict__ bq, const float* __restrict__ bk, const float* __restrict__ bv,
    unsigned short* __restrict__ q_bf,       // [4096][1024]
    unsigned short* __restrict__ k_bf,       // [4096][128]
    unsigned short* __restrict__ vt_bf)      // [128][4096]
{
    __shared__ unsigned short SM[32768];     // As[2][8192] | Bs[2][8192] (64KB)
    unsigned short* As = SM;                 // As[buf] = SM + buf*8192
    unsigned short* Bs = SM + 16384;
    const int t = threadIdx.x;
    const int lane = t & 63, wave = t >> 6;
    const int l15 = lane & 15, quad = lane >> 4;
    const int m0 = blockIdx.x * 128, n0 = blockIdx.y * 128;
    const int wm = (wave >> 1) * 64, wn = (wave & 1) * 64;
    const int srow_l = lane >> 3;    // 0..7 within an 8-row/1KB window
    const int sc_phys = lane & 7;

    f32x4 acc[4][4];
#pragma unroll
    for (int i = 0; i < 4; ++i)
#pragma unroll
        for (int j = 0; j < 4; ++j) acc[i][j] = (f32x4)0.0f;

    auto issue = [&](int k0c, int buf) {
        int c = sc_phys ^ srow_l;
#pragma unroll
        for (int p = 0; p < 4; ++p) {   // A: 16 windows of 8 rows = 128
            int rb = (wave * 4 + p) * 8;
            dma16(&xb[(m0 + rb + srow_l) * 1024 + k0c + c * 8], &As[buf * 8192 + rb * 64]);
            dma16(&Wt[(n0 + rb + srow_l) * 1024 + k0c + c * 8], &Bs[buf * 8192 + rb * 64]);
        }
    };

    issue(0, 0);
    for (int kst = 0; kst < 16; ++kst) {
        const int buf = kst & 1;
        __syncthreads();
        if (kst < 15) issue((kst + 1) * 64, buf ^ 1);
#pragma unroll
        for (int ks = 0; ks < 2; ++ks) {
            bf16x8 a[4], b[4];
#pragma unroll
            for (int mt = 0; mt < 4; ++mt)
                a[mt] = *(const bf16x8*)&As[buf * 8192 + (wm + mt * 16 + l15) * 64 + (((ks * 4 + quad) ^ (l15 & 7)) * 8)];
#pragma unroll
            for (int nt = 0; nt < 4; ++nt)
                b[nt] = *(const bf16x8*)&Bs[buf * 8192 + (wn + nt * 16 + l15) * 64 + (((ks * 4 + quad) ^ (l15 & 7)) * 8)];
#pragma unroll
            for (int mt = 0; mt < 4; ++mt)
#pragma unroll
                for (int nt = 0; nt < 4; ++nt)
                    acc[mt][nt] = __builtin_amdgcn_mfma_f32_16x16x32_bf16(a[mt], b[nt], acc[mt][nt], 0, 0, 0);
        }
    }

    // qscale = log2(e)/sqrt(128): attention uses exp2
    const float qscale = 0.08838834764831843f * 1.4426950408889634f;
    if (blockIdx.y < 8) {            // pure q block
#pragma unroll
        for (int mt = 0; mt < 4; ++mt)
#pragma unroll
            for (int nt = 0; nt < 4; ++nt) {
                int row = m0 + wm + mt * 16 + quad * 4;
                int col = n0 + wn + nt * 16 + l15;
                float b = bq[col];
                uint32_t u01 = cvt2_bf16((acc[mt][nt][0] + b) * qscale, (acc[mt][nt][1] + b) * qscale);
                uint32_t u23 = cvt2_bf16((acc[mt][nt][2] + b) * qscale, (acc[mt][nt][3] + b) * qscale);
                q_bf[(row + 0) * 1024 + col] = (unsigned short)u01;
                q_bf[(row + 1) * 1024 + col] = (unsigned short)(u01 >> 16);
                q_bf[(row + 2) * 1024 + col] = (unsigned short)u23;
                q_bf[(row + 3) * 1024 + col] = (unsigned short)(u23 >> 16);
            }
    } else if (blockIdx.y == 8) {    // pure k block
#pragma unroll
        for (int mt = 0; mt < 4; ++mt)
#pragma unroll
            for (int nt = 0; nt < 4; ++nt) {
                int row = m0 + wm + mt * 16 + quad * 4;
                int col = wn + nt * 16 + l15;
                float b = bk[col];
                uint32_t u01 = cvt2_bf16(acc[mt][nt][0] + b, acc[mt][nt][1] + b);
                uint32_t u23 = cvt2_bf16(acc[mt][nt][2] + b, acc[mt][nt][3] + b);
                k_bf[(row + 0) * 128 + col] = (unsigned short)u01;
                k_bf[(row + 1) * 128 + col] = (unsigned short)(u01 >> 16);
                k_bf[(row + 2) * 128 + col] = (unsigned short)u23;
                k_bf[(row + 3) * 128 + col] = (unsigned short)(u23 >> 16);
            }
    } else {                         // pure v block: LDS transpose, coalesced store
        unsigned short* T = SM;      // [128 cols][136] = 34.8KB <= 64KB
        __syncthreads();             // staging LDS dead
#pragma unroll
        for (int mt = 0; mt < 4; ++mt)
#pragma unroll
            for (int nt = 0; nt < 4; ++nt) {
                int lrow = wm + mt * 16 + quad * 4;
                int lc = wn + nt * 16 + l15;
                float b = bv[lc];
                uint2 u;
                u.x = cvt2_bf16(acc[mt][nt][0] + b, acc[mt][nt][1] + b);
                u.y = cvt2_bf16(acc[mt][nt][2] + b, acc[mt][nt][3] + b);
                *(uint2*)&T[lc * 136 + lrow] = u;
            }
        __syncthreads();
        int dr = t >> 1;             // d row 0..127
#pragma unroll
        for (int p = 0; p < 8; ++p) {
            int idx = (t & 1) * 8 + p;             // 16B chunk within 256B row
            int4 d = *(const int4*)&T[dr * 136 + idx * 8];
            *(int4*)&vt_bf[dr * 4096 + m0 + idx * 8] = d;
        }
    }
}

// ---------------- kernel 2: flash attention (MQA) -----------
// 256 blocks x 512 thr. Waves 0-3: keys 0..2047; 4-7: 2048..4095.
// Wave = 16 q-rows x 2 heads. Computes S^T (operand-swapped MFMA) so P
// lands with lane = q-row, 4 consecutive keys -> b64 P-writes.
// l via constant ones B-fragment (no LDS column).
__global__ __launch_bounds__(512, 1) void mqa_attn(
    const unsigned short* __restrict__ q_bf,   // [4096][1024], pre-scaled by log2e/sqrt(d)
    const unsigned short* __restrict__ k_bf,   // [4096][128]
    const unsigned short* __restrict__ vt_bf,  // [128][4096]
    float* __restrict__ out)                   // [4096][1024]
{
    __shared__ unsigned short Ks[2][2][64 * 128];   // [half][buf][key][d] swizzled (64KB)
    __shared__ unsigned short Vs[2][128 * 64];      // [half][d][key] swizzled (32KB)
    __shared__ unsigned short Ps[8][2][16 * 72];    // per-wave, per-head P (A-layout) (36KB)
    const int t = threadIdx.x;
    const int lane = t & 63, wave = t >> 6;
    const int l15 = lane & 15, quad = lane >> 4;
    const int half = wave >> 2, w2 = wave & 3;
    const int qbase = blockIdx.x * 32 + (w2 & 1) * 16;
    const int h0 = blockIdx.y * 4 + (w2 >> 1) * 2;
    const int kbase = half * 2048;

    const int krow_l = lane >> 4;    // 0..3 (256B K rows)
    const int kc_phys = lane & 15;
    const int vrow_l = lane >> 3;    // 0..7 (128B V rows)
    const int vc_phys = lane & 7;

    // constant ones B-fragment: B[k][n]: col n=l15; ones column is n==0
    bf16x8 onesf;
#pragma unroll
    for (int j = 0; j < 8; ++j) onesf[j] = (l15 == 0) ? (short)0x3F80 : (short)0;

    // Q fragments (A/B-layout, identical index math), both heads
    bf16x8 qf[2][4];
    {
        int qrow = qbase + l15;
#pragma unroll
        for (int g = 0; g < 2; ++g)
#pragma unroll
            for (int ks = 0; ks < 4; ++ks)
                qf[g][ks] = *(const bf16x8*)&q_bf[qrow * 1024 + (h0 + g) * 128 + ks * 32 + quad * 8];
    }

    f32x4 o[2][9];                   // [head][d-window]; window 8 = l (ones frag)
#pragma unroll
    for (int g = 0; g < 2; ++g)
#pragma unroll
        for (int d = 0; d < 9; ++d) o[g][d] = (f32x4)0.0f;

    auto issueK = [&](int kt, int buf) {
#pragma unroll
        for (int p = 0; p < 4; ++p) {
            int row = w2 * 16 + p * 4 + krow_l;
            int c = kc_phys ^ (row & 15);
            dma16(&k_bf[(kt + row) * 128 + c * 8], &Ks[half][buf][(w2 * 16 + p * 4) * 128]);
        }
    };
    auto issueV = [&](int kt) {
#pragma unroll
        for (int p = 0; p < 4; ++p) {
            int row = w2 * 32 + p * 8 + vrow_l;
            int c = vc_phys ^ vrow_l;
            dma16(&vt_bf[row * 4096 + kt + c * 8], &Vs[half][(w2 * 32 + p * 8) * 64]);
        }
    };

    issueK(kbase, 0);
    for (int it = 0; it < 32; ++it) {
        const int buf = it & 1;
        __syncthreads();                 // drains K(it) [+V(it-1)]
        issueV(kbase + it * 64);         // V first (older in vmcnt order)
        const bool pk = (it + 1 < 32);
        if (pk) issueK(kbase + (it + 1) * 64, buf ^ 1);

        // S^T = K Q^T (operand-swapped): D[m=key_local][n=q]
        // C-layout: qrow = l15, key = nt*16 + quad*4 + reg
        f32x4 s[2][4];
#pragma unroll
        for (int g = 0; g < 2; ++g)
#pragma unroll
            for (int nt = 0; nt < 4; ++nt) s[g][nt] = (f32x4)0.0f;
#pragma unroll
        for (int ks = 0; ks < 4; ++ks)
#pragma unroll
            for (int nt = 0; nt < 4; ++nt) {
                int row = nt * 16 + l15;
                bf16x8 kb = *(const bf16x8*)&Ks[half][buf][row * 128 + (((ks * 4 + quad) ^ l15) * 8)];
                s[0][nt] = __builtin_amdgcn_mfma_f32_16x16x32_bf16(kb, qf[0][ks], s[0][nt], 0, 0, 0);
                s[1][nt] = __builtin_amdgcn_mfma_f32_16x16x32_bf16(kb, qf[1][ks], s[1][nt], 0, 0, 0);
            }

        // p = exp2(s); pack 4 consecutive keys for this lane's q-row -> b64 write
#pragma unroll
        for (int g = 0; g < 2; ++g) {
            unsigned short* P = &Ps[wave][g][0];
#pragma unroll
            for (int nt = 0; nt < 4; ++nt) {
                float p0 = __builtin_amdgcn_exp2f(s[g][nt][0]);
                float p1 = __builtin_amdgcn_exp2f(s[g][nt][1]);
                float p2 = __builtin_amdgcn_exp2f(s[g][nt][2]);
                float p3 = __builtin_amdgcn_exp2f(s[g][nt][3]);
                uint2 u;
                u.x = cvt2_bf16(p0, p1);
                u.y = cvt2_bf16(p2, p3);
                *(uint2*)&P[l15 * 72 + nt * 16 + quad * 4] = u;   // P[qrow][key..key+3]
            }
        }
        asm volatile("s_waitcnt lgkmcnt(0)" ::: "memory");
        // wait for V(it) only; keep K(it+1) in flight
        if (pk) asm volatile("s_waitcnt vmcnt(4)" ::: "memory");
        else    asm volatile("s_waitcnt vmcnt(0)" ::: "memory");

        // O += P V ; l accumulates in window 8 via constant ones fragment
#pragma unroll
        for (int ks = 0; ks < 2; ++ks) {
            bf16x8 pa0 = *(const bf16x8*)&Ps[wave][0][l15 * 72 + ks * 32 + quad * 8];
            bf16x8 pa1 = *(const bf16x8*)&Ps[wave][1][l15 * 72 + ks * 32 + quad * 8];
#pragma unroll
            for (int d = 0; d < 8; ++d) {
                int row = d * 16 + l15;
                bf16x8 vb = *(const bf16x8*)&Vs[half][row * 64 + (((ks * 4 + quad) ^ (l15 & 7)) * 8)];
                o[0][d] = __builtin_amdgcn_mfma_f32_16x16x32_bf16(pa0, vb, o[0][d], 0, 0, 0);
                o[1][d] = __builtin_amdgcn_mfma_f32_16x16x32_bf16(pa1, vb, o[1][d], 0, 0, 0);
            }
            o[0][8] = __builtin_amdgcn_mfma_f32_16x16x32_bf16(pa0, onesf, o[0][8], 0, 0, 0);
            o[1][8] = __builtin_amdgcn_mfma_f32_16x16x32_bf16(pa1, onesf, o[1][8], 0, 0, 0);
        }
    }

    // combine halves through LDS (staging areas dead)
    __syncthreads();
    float* Xo = (float*)&Ks[0][0][0];    // 4 x 16 slots x 64 lanes x f32x4 = 64KB
    float* Xl = (float*)&Vs[0][0];       // 4 x 2 slots  x 64 lanes x f32x4 = 8KB
    if (half == 1) {
#pragma unroll
        for (int g = 0; g < 2; ++g) {
#pragma unroll
            for (int d = 0; d < 8; ++d)
                *(f32x4*)&Xo[((w2 * 16 + g * 8 + d) * 64 + lane) * 4] = o[g][d];
            *(f32x4*)&Xl[((w2 * 2 + g) * 64 + lane) * 4] = o[g][8];
        }
    }
    __syncthreads();
    if (half == 0) {
#pragma unroll
        for (int g = 0; g < 2; ++g) {
#pragma unroll
            for (int d = 0; d < 8; ++d)
                o[g][d] += *(const f32x4*)&Xo[((w2 * 16 + g * 8 + d) * 64 + lane) * 4];
            f32x4 o8 = o[g][8] + *(const f32x4*)&Xl[((w2 * 2 + g) * 64 + lane) * 4];
#pragma unroll
            for (int r = 0; r < 4; ++r) {
                float l = __shfl(o8[r], lane & 48, 64);   // col-0 lane of this quad
                float inv = 1.0f / l;
                int row = qbase + quad * 4 + r;
#pragma unroll
                for (int d = 0; d < 8; ++d)
                    out[row * 1024 + (h0 + g) * 128 + d * 16 + l15] = o[g][d][r] * inv;
            }
        }
    }
}

// ---------------- launch ------------------------------------
extern "C" void kernel_launch(void* const* d_in, const int* in_sizes, int n_in,
                              void* d_out, int out_size, void* d_ws, size_t ws_size,
                              hipStream_t stream) {
    const float* x  = (const float*)d_in[0];
    const float* Wq = (const float*)d_in[1];
    const float* bq = (const float*)d_in[2];
    const float* Wk = (const float*)d_in[3];
    const float* bk = (const float*)d_in[4];
    const float* Wv = (const float*)d_in[5];
    const float* bv = (const float*)d_in[6];
    float* out = (float*)d_out;

    char* ws = (char*)d_ws;
    unsigned short* xb = (unsigned short*)(ws);                    // 8 MB  [4096][1024]
    unsigned short* Wt = (unsigned short*)(ws + 8388608);          // 2.5MB [1280][1024]
    unsigned short* qb = (unsigned short*)(ws + 11010048);         // 8 MB  [4096][1024]
    unsigned short* kb = (unsigned short*)(ws + 19398656);         // 1 MB  [4096][128]
    unsigned short* vt = (unsigned short*)(ws + 20447232);         // 1 MB  [128][4096]

    prep<<<2368, 256, 0, stream>>>((const float4*)x, (int4*)xb, Wq, Wk, Wv, Wt);
    qkv_gemm<<<dim3(32, 10), 256, 0, stream>>>(xb, Wt, bq, bk, bv, qb, kb, vt);
    mqa_attn<<<dim3(SEQ / 32, 2), 512, 0, stream>>>(qb, kb, vt, out);
}